// Round 4
// baseline (881.919 us; speedup 1.0000x reference)
//
#include <hip/hip_runtime.h>
#include <math.h>

#define HD 128      // hidden dim (= F_IN)
#define ED 16       // edge feat dim
#define NG 64       // num graphs
#define NC 10       // num classes

typedef short bf16x8 __attribute__((ext_vector_type(8)));
typedef float f32x4 __attribute__((ext_vector_type(4)));

__device__ __forceinline__ unsigned short f2b(float x){
  unsigned u = __float_as_uint(x);
  unsigned r = (u + 0x7fffu + ((u >> 16) & 1u)) >> 16;
  return (unsigned short)r;
}
__device__ __forceinline__ float blo(unsigned p){ return __uint_as_float(p << 16); }
__device__ __forceinline__ float bhi(unsigned p){ return __uint_as_float(p & 0xffff0000u); }

// ---------------- CSR build ----------------
__global__ void k_hist(const int* __restrict__ dst, int* __restrict__ deg, int E){
  int e = blockIdx.x*blockDim.x + threadIdx.x;
  if(e<E) atomicAdd(&deg[dst[e]], 1);
}

__global__ __launch_bounds__(64) void k_bsum(const int* __restrict__ deg, int* __restrict__ bsum, int N){
  int b = blockIdx.x, t = threadIdx.x;
  int i = b*256 + t*4;
  int s = 0;
  if(i+3 < N){ int4 v = *(const int4*)&deg[i]; s = v.x+v.y+v.z+v.w; }
  else { for(int k=0;k<4;k++) if(i+k<N) s += deg[i+k]; }
  #pragma unroll
  for(int o=32;o;o>>=1) s += __shfl_xor(s,o);
  if(t==0) bsum[b] = s;
}

__global__ __launch_bounds__(1024) void k_bscan(const int* __restrict__ bsum, int* __restrict__ bbase,
                                                int* __restrict__ offs, int N, int nb){
  __shared__ int sh[1024];
  int t = threadIdx.x;
  int v = (t < nb) ? bsum[t] : 0;
  sh[t] = v; __syncthreads();
  for(int o=1;o<1024;o<<=1){ int u = (t>=o)?sh[t-o]:0; __syncthreads(); sh[t]+=u; __syncthreads(); }
  if(t < nb) bbase[t] = sh[t] - v;
  if(t == 1023) offs[N] = sh[1023];
}

__global__ __launch_bounds__(256) void k_bprop(const int* __restrict__ deg, const int* __restrict__ bbase,
                                               int* __restrict__ offs, int* __restrict__ cursor, int N){
  __shared__ int sh[256];
  int b = blockIdx.x, t = threadIdx.x;
  int i = b*256 + t;
  int v = (i<N) ? deg[i] : 0;
  sh[t] = v; __syncthreads();
  for(int o=1;o<256;o<<=1){ int u = (t>=o)?sh[t-o]:0; __syncthreads(); sh[t]+=u; __syncthreads(); }
  if(i<N){ int o_ = bbase[b] + sh[t] - v; offs[i] = o_; cursor[i] = o_; }
}

__global__ void k_scatter(const int* __restrict__ src, const int* __restrict__ dst,
                          int* __restrict__ cursor, int* __restrict__ pos,
                          int* __restrict__ src_csr, int* __restrict__ dst_csr, int E){
  int e = blockIdx.x*blockDim.x + threadIdx.x;
  if(e<E){
    int d = dst[e];
    int p = atomicAdd(&cursor[d], 1);
    pos[e] = p;
    src_csr[p] = src[e];
    dst_csr[p] = d;
  }
}

__global__ void k_eq(const float* __restrict__ ef,
                     const float* __restrict__ a1e, const float* __restrict__ a2e, const float* __restrict__ a3e,
                     const int* __restrict__ pos, float* __restrict__ q, int E){
  int e = blockIdx.x*blockDim.x + threadIdx.x;
  if(e>=E) return;
  const float* f = &ef[(size_t)e*ED];
  float q1=0.f, q2=0.f, q3=0.f;
  #pragma unroll
  for(int i=0;i<ED;i++){
    float fv = f[i];
    q1 = fmaf(fv, a1e[i], q1);
    q2 = fmaf(fv, a2e[i], q2);
    q3 = fmaf(fv, a3e[i], q3);
  }
  int j = pos[e];
  q[j] = q1; q[(size_t)E + j] = q2; q[2*(size_t)E + j] = q3;
}

// ---------------- fp32 -> bf16 cast (x input) ----------------
__global__ void k_cast(const float* __restrict__ x, unsigned short* __restrict__ xb, int n){
  int i = (blockIdx.x*blockDim.x + threadIdx.x)*8;
  if(i >= n) return;
  float4 v0 = *(const float4*)&x[i];
  float4 v1 = *(const float4*)&x[i+4];
  uint4 o;
  o.x = f2b(v0.x) | ((unsigned)f2b(v0.y)<<16);
  o.y = f2b(v0.z) | ((unsigned)f2b(v0.w)<<16);
  o.z = f2b(v1.x) | ((unsigned)f2b(v1.y)<<16);
  o.w = f2b(v1.z) | ((unsigned)f2b(v1.w)<<16);
  *(uint4*)&xb[i] = o;
}

// ---------------- W -> B-fragment-swizzled bf16 (all 3 layers) ----------------
// Layout: Wb[((kt*8+nt)*64 + lane)*8 + j] = bf16(W[kt*32 + (lane>>4)*8 + j][nt*16 + (lane&15)])
__global__ __launch_bounds__(256) void k_wswiz(const float* __restrict__ W1, const float* __restrict__ W2,
                        const float* __restrict__ W3, unsigned short* __restrict__ Wb){
  int idx = blockIdx.x*256 + threadIdx.x;    // 3 * 2048
  if(idx >= 3*2048) return;
  int layer = idx >> 11;
  int r = idx & 2047;
  const float* W = (layer==0)?W1:((layer==1)?W2:W3);
  int lane = r & 63, tile = r >> 6;
  int kt = tile >> 3, nt = tile & 7;
  int qq = lane >> 4, cc = lane & 15;
  int kbase = kt*32 + qq*8;
  int col = nt*16 + cc;
  unsigned short tmp[8];
  #pragma unroll
  for(int j=0;j<8;j++) tmp[j] = f2b(W[(size_t)(kbase+j)*HD + col]);
  uint4 o;
  o.x = tmp[0]|((unsigned)tmp[1]<<16); o.y = tmp[2]|((unsigned)tmp[3]<<16);
  o.z = tmp[4]|((unsigned)tmp[5]<<16); o.w = tmp[6]|((unsigned)tmp[7]<<16);
  *(uint4*)&Wb[(size_t)idx*8] = o;
}

// ---------------- MFMA GEMM: Zb[M x 128](bf16) = Ab @ W, fused pdots ----------------
// block = 256 thr = 4 waves; wave covers 32 rows (2 row-tiles of 16); K=128 in 4 steps of 32.
__global__ __launch_bounds__(256) void k_gemm_mfma(
    const unsigned short* __restrict__ Ab,   // M x 128 bf16 row-major
    const unsigned short* __restrict__ Wb,   // swizzled B-frags
    unsigned short* __restrict__ Zb,         // M x 128 bf16 out
    const float* __restrict__ avec,          // a: [a_src(128) | a_dst(128) | a_e(16)]
    float* __restrict__ ps, float* __restrict__ pd, int M)
{
  int tid = threadIdx.x;
  int w = tid >> 6, lane = tid & 63;
  int q = lane >> 4, c = lane & 15;
  int rowbase = blockIdx.x*128 + w*32;
  f32x4 acc[2][8];
  #pragma unroll
  for(int t=0;t<2;t++)
    #pragma unroll
    for(int n=0;n<8;n++) acc[t][n] = (f32x4){0.f,0.f,0.f,0.f};

  int r0 = rowbase + c;      if(r0 > M-1) r0 = M-1;
  int r1 = rowbase + 16 + c; if(r1 > M-1) r1 = M-1;
  #pragma unroll
  for(int kt=0; kt<4; kt++){
    int ko = kt*32 + q*8;
    bf16x8 a0 = __builtin_bit_cast(bf16x8, *(const uint4*)&Ab[(size_t)r0*HD + ko]);
    bf16x8 a1 = __builtin_bit_cast(bf16x8, *(const uint4*)&Ab[(size_t)r1*HD + ko]);
    #pragma unroll
    for(int n=0;n<8;n++){
      bf16x8 b = __builtin_bit_cast(bf16x8, *(const uint4*)&Wb[(((size_t)(kt*8+n))*64 + lane)*8]);
      acc[0][n] = __builtin_amdgcn_mfma_f32_16x16x32_bf16(a0, b, acc[0][n], 0,0,0);
      acc[1][n] = __builtin_amdgcn_mfma_f32_16x16x32_bf16(a1, b, acc[1][n], 0,0,0);
    }
  }
  float asv[8], adv[8];
  #pragma unroll
  for(int n=0;n<8;n++){ asv[n] = avec[n*16+c]; adv[n] = avec[HD + n*16+c]; }
  #pragma unroll
  for(int t=0;t<2;t++){
    #pragma unroll
    for(int r=0;r<4;r++){
      int grow = rowbase + t*16 + 4*q + r;
      bool ok = grow < M;
      #pragma unroll
      for(int n=0;n<8;n++){
        if(ok) Zb[(size_t)grow*HD + n*16 + c] = f2b(acc[t][n][r]);
      }
      float pp = 0.f, dd = 0.f;
      #pragma unroll
      for(int n=0;n<8;n++){ pp = fmaf(acc[t][n][r], asv[n], pp); dd = fmaf(acc[t][n][r], adv[n], dd); }
      #pragma unroll
      for(int o=1;o<16;o<<=1){ pp += __shfl_xor(pp,o); dd += __shfl_xor(dd,o); }
      if(ok && c==0){ ps[grow] = pp; pd[grow] = dd; }
    }
  }
}

// ---------------- edge logits in CSR order (leaky 0.2) ----------------
__global__ void k_logits(const float* __restrict__ ps, const float* __restrict__ pd,
                         const int* __restrict__ src_csr, const int* __restrict__ dst_csr,
                         const float* __restrict__ q, float* __restrict__ lg, int E){
  int j = blockIdx.x*blockDim.x + threadIdx.x;
  if(j>=E) return;
  float l = ps[src_csr[j]] + pd[dst_csr[j]] + q[j];
  lg[j] = (l >= 0.f) ? l : 0.2f*l;
}

// ---------------- softmax + quad-parallel aggregate + relu + att + fused readout ----------------
__global__ __launch_bounds__(256) void k_agg(const uint4* __restrict__ zb4,   // node rows: 16 uint4
                                             const float* __restrict__ lg,
                                             const int* __restrict__ offs,
                                             const int* __restrict__ src_csr,
                                             const int* __restrict__ gid,
                                             unsigned* __restrict__ hbu,      // N x 64 uints (bf16 h out)
                                             const float* __restrict__ watt,
                                             const float* __restrict__ batt,
                                             float* __restrict__ hg, int N){
  int wid = blockIdx.x*4 + (threadIdx.x>>6);
  int lane = threadIdx.x & 63;
  if(wid >= N) return;
  int q = lane >> 4, c = lane & 15;
  int d0 = offs[wid], d1 = offs[wid+1];
  // pass 1: max over logits (contiguous)
  float m = -INFINITY;
  for(int j=d0+lane; j<d1; j+=64) m = fmaxf(m, lg[j]);
  #pragma unroll
  for(int o=32;o;o>>=1) m = fmaxf(m, __shfl_xor(m,o));
  // pass 2: fused sum-of-exp + weighted gather; quad q handles edge j+q
  float acc[8];
  #pragma unroll
  for(int i=0;i<8;i++) acc[i]=0.f;
  float ssum = 0.f;
  for(int j=d0; j<d1; j+=4){
    int jq = j + q;
    bool v = jq < d1;
    int e = v ? jq : (d1-1);
    float wgt = v ? __expf(lg[e] - m) : 0.f;
    int u = src_csr[e];
    uint4 P = zb4[(size_t)u*16 + c];
    ssum += wgt;
    acc[0] = fmaf(wgt, blo(P.x), acc[0]); acc[1] = fmaf(wgt, bhi(P.x), acc[1]);
    acc[2] = fmaf(wgt, blo(P.y), acc[2]); acc[3] = fmaf(wgt, bhi(P.y), acc[3]);
    acc[4] = fmaf(wgt, blo(P.z), acc[4]); acc[5] = fmaf(wgt, bhi(P.z), acc[5]);
    acc[6] = fmaf(wgt, blo(P.w), acc[6]); acc[7] = fmaf(wgt, bhi(P.w), acc[7]);
  }
  // reduce across quads (lanes with same c)
  #pragma unroll
  for(int i=0;i<8;i++){ acc[i] += __shfl_xor(acc[i],16); acc[i] += __shfl_xor(acc[i],32); }
  ssum += __shfl_xor(ssum,16); ssum += __shfl_xor(ssum,32);
  float inv = (d1 > d0) ? 1.0f/ssum : 0.0f;
  #pragma unroll
  for(int i=0;i<8;i++) acc[i] = fmaxf(acc[i]*inv, 0.f);   // normalize + relu
  // store h (bf16): lane writes cols c*8+2q, c*8+2q+1
  hbu[(size_t)wid*64 + c*4 + q] = (unsigned)f2b(acc[2*q]) | ((unsigned)f2b(acc[2*q+1])<<16);
  // att scalar: every lane holds cols c*8..c*8+7
  float4 w0 = *(const float4*)&watt[c*8];
  float4 w1 = *(const float4*)&watt[c*8+4];
  float t = acc[0]*w0.x + acc[1]*w0.y + acc[2]*w0.z + acc[3]*w0.w
          + acc[4]*w1.x + acc[5]*w1.y + acc[6]*w1.z + acc[7]*w1.w;
  #pragma unroll
  for(int o=1;o<16;o<<=1) t += __shfl_xor(t,o);
  t += batt[0];
  float lr = (t >= 0.f) ? t : 0.01f*t;
  float attv = __expf(lr);
  // fused readout: hg[g] += attv * h
  int g = gid[wid];
  atomicAdd(&hg[g*HD + c*8 + 2*q],     attv*acc[2*q]);
  atomicAdd(&hg[g*HD + c*8 + 2*q + 1], attv*acc[2*q+1]);
}

// ---------------- per-graph node counts ----------------
__global__ __launch_bounds__(64) void k_cnt(const int* __restrict__ gid, float* __restrict__ cnt, int N){
  int g = threadIdx.x;
  if(g >= NG) return;
  int lo=0, hi=N;
  while(lo<hi){ int mid=(lo+hi)>>1; if(gid[mid] < g) lo=mid+1; else hi=mid; }
  int start = lo; lo = start; hi = N;
  while(lo<hi){ int mid=(lo+hi)>>1; if(gid[mid] < g+1) lo=mid+1; else hi=mid; }
  cnt[g] = (float)(lo - start);
}

// ---------------- final classifier + log_softmax ----------------
__global__ __launch_bounds__(256) void k_final(const float* __restrict__ hg,
                                               const float* __restrict__ cnt,
                                               const float* __restrict__ Wc,
                                               const float* __restrict__ bc,
                                               float* __restrict__ out){
  __shared__ float y[NG][NC];
  int tid = threadIdx.x;
  for(int idx=tid; idx<NG*NC; idx+=256){
    int g = idx / NC, c = idx % NC;
    float invc = 1.f / fmaxf(cnt[g], 1.f);
    float s = bc[c];
    #pragma unroll
    for(int part=0; part<3; part++){
      const float* row = &hg[part*NG*HD + g*HD];
      for(int f=0; f<HD; f++) s = fmaf(row[f]*invc, Wc[(part*HD+f)*NC + c], s);
    }
    y[g][c] = s;
  }
  __syncthreads();
  if(tid < NG){
    float mx = -INFINITY;
    #pragma unroll
    for(int c=0;c<NC;c++) mx = fmaxf(mx, y[tid][c]);
    float s = 0.f;
    #pragma unroll
    for(int c=0;c<NC;c++) s += __expf(y[tid][c] - mx);
    float ls = logf(s);
    #pragma unroll
    for(int c=0;c<NC;c++) out[tid*NC + c] = y[tid][c] - mx - ls;
  }
}

// ---------------- host ----------------
extern "C" void kernel_launch(void* const* d_in, const int* in_sizes, int n_in,
                              void* d_out, int out_size, void* d_ws, size_t ws_size,
                              hipStream_t stream) {
  const float* x     = (const float*)d_in[0];
  const float* efeat = (const float*)d_in[1];
  const int*   src   = (const int*)d_in[2];
  const int*   dst   = (const int*)d_in[3];
  const int*   gid   = (const int*)d_in[4];
  const float* W1    = (const float*)d_in[5];
  const float* a1    = (const float*)d_in[6];
  const float* W2    = (const float*)d_in[7];
  const float* a2    = (const float*)d_in[8];
  const float* W3    = (const float*)d_in[9];
  const float* a3    = (const float*)d_in[10];
  const float* watt  = (const float*)d_in[11];
  const float* batt  = (const float*)d_in[12];
  const float* Wc    = (const float*)d_in[13];
  const float* bc    = (const float*)d_in[14];
  float* out = (float*)d_out;

  int N = in_sizes[4];
  int E = in_sizes[2];

  char* p = (char*)d_ws;
  auto alloc = [&](size_t bytes)->void*{
    void* r = (void*)p;
    p += (bytes + 255) & ~(size_t)255;
    return r;
  };
  unsigned short* Xb = (unsigned short*)alloc((size_t)N*HD*2);  // x bf16
  unsigned short* Hb = (unsigned short*)alloc((size_t)N*HD*2);  // h bf16
  unsigned short* Zb = (unsigned short*)alloc((size_t)N*HD*2);  // z bf16
  unsigned short* Wball = (unsigned short*)alloc((size_t)3*2048*8*2);
  float* ps      = (float*)alloc((size_t)N*4);
  float* pd      = (float*)alloc((size_t)N*4);
  int*   deg     = (int*)  alloc((size_t)N*4);
  int*   offs    = (int*)  alloc((size_t)(N+1)*4);
  int*   cursor  = (int*)  alloc((size_t)N*4);
  int*   pos     = (int*)  alloc((size_t)E*4);
  int*   src_csr = (int*)  alloc((size_t)E*4);
  int*   dst_csr = (int*)  alloc((size_t)E*4);
  float* qcsr    = (float*)alloc((size_t)3*E*4);
  float* lgits   = (float*)alloc((size_t)E*4);
  int*   bsum    = (int*)  alloc((size_t)1024*4);
  int*   bbase   = (int*)  alloc((size_t)1024*4);
  float* hg      = (float*)alloc((size_t)3*NG*HD*4);
  float* cnt     = (float*)alloc((size_t)NG*4);
  (void)ws_size; (void)n_in; (void)out_size;

  int ethreads = 256;
  int eblocks = (E + ethreads - 1) / ethreads;
  int nwblocks = (N + 3) / 4;
  int nb = (N + 255) / 256;

  hipMemsetAsync(deg, 0, (size_t)N*4, stream);
  hipMemsetAsync(hg, 0, (size_t)3*NG*HD*4, stream);
  k_hist<<<eblocks, ethreads, 0, stream>>>(dst, deg, E);
  k_bsum<<<nb, 64, 0, stream>>>(deg, bsum, N);
  k_bscan<<<1, 1024, 0, stream>>>(bsum, bbase, offs, N, nb);
  k_bprop<<<nb, 256, 0, stream>>>(deg, bbase, offs, cursor, N);
  k_scatter<<<eblocks, ethreads, 0, stream>>>(src, dst, cursor, pos, src_csr, dst_csr, E);
  k_eq<<<eblocks, ethreads, 0, stream>>>(efeat, a1+2*HD, a2+2*HD, a3+2*HD, pos, qcsr, E);
  k_cast<<<((N*HD/8) + 255)/256, 256, 0, stream>>>(x, Xb, N*HD);
  k_wswiz<<<24, 256, 0, stream>>>(W1, W2, W3, Wball);
  k_cnt<<<1, 64, 0, stream>>>(gid, cnt, N);

  const float* as[3] = {a1, a2, a3};
  for(int layer=0; layer<3; layer++){
    const unsigned short* Ab = (layer==0) ? Xb : Hb;
    k_gemm_mfma<<<(N+127)/128, 256, 0, stream>>>(Ab, Wball + (size_t)layer*2048*8, Zb,
                                                 as[layer], ps, pd, N);
    k_logits<<<eblocks, ethreads, 0, stream>>>(ps, pd, src_csr, dst_csr,
                                               qcsr + (size_t)layer*E, lgits, E);
    k_agg<<<nwblocks, 256, 0, stream>>>((const uint4*)Zb, lgits, offs, src_csr, gid,
                                        (unsigned*)Hb, watt, batt, hg + (size_t)layer*NG*HD, N);
  }
  k_final<<<1, 256, 0, stream>>>(hg, cnt, Wc, bc, out);
}